// Round 3
// baseline (387.186 us; speedup 1.0000x reference)
//
#include <hip/hip_runtime.h>
#include <hip/hip_fp16.h>

#define C 4096
#define NN 110
#define MPAD 112

typedef _Float16 f16x8 __attribute__((ext_vector_type(8)));
typedef float fx4 __attribute__((ext_vector_type(4)));
typedef unsigned long long ull;

// ---------------------------------------------------------------------------
// prep1: A1[112][4096] = fp16(x), rows >=110 zeroed. u32 pair stores.
// ---------------------------------------------------------------------------
__global__ __launch_bounds__(256)
void prep1_kernel(const float* __restrict__ x, _Float16* __restrict__ A1) {
    int idx = blockIdx.x * 256 + threadIdx.x;     // pair index, 112*2048 total
    int n = idx >> 11;
    union { _Float16 h[2]; unsigned u; } pk;
    pk.u = 0;
    if (n < NN) {
        float2 v = *(const float2*)(x + 2 * (size_t)idx);
        pk.h[0] = (_Float16)v.x;
        pk.h[1] = (_Float16)v.y;
    }
    ((unsigned*)A1)[idx] = pk.u;
}

// ---------------------------------------------------------------------------
// maskprep: once-only adjacency bitmasks + degrees (was recomputed 256x in agg)
// ---------------------------------------------------------------------------
__global__ __launch_bounds__(128)
void maskprep_kernel(const int* __restrict__ adj, ull* __restrict__ mlo,
                     ull* __restrict__ mhi, float* __restrict__ degs) {
    int j = threadIdx.x;
    if (j < NN) {
        ull lo = 0, hi = 0; int dg = 0;
        for (int i = 0; i < 64; ++i) {
            int m = (adj[i * NN + j] != 0);
            lo |= ((ull)m) << i; dg += m;
        }
        for (int i = 64; i < NN; ++i) {
            int m = (adj[i * NN + j] != 0);
            hi |= ((ull)m) << (i - 64); dg += m;
        }
        mlo[j] = lo; mhi[j] = hi;
        degs[j] = (float)(dg > 0 ? dg : 1);
    }
}

// ---------------------------------------------------------------------------
// mm: Cacc[0:110,:] += A16[0:112, kchunk] @ fp16(B[kchunk, :])
//  - A-fragments loaded DIRECT from global (A is L2-resident, frag = 16B run)
//  - B staged via regs -> LDS (transpose+cvt), XOR-swizzled 16B granules
//  - counted-vmcnt 3-deep pipeline: COMMIT(it+1) waits with A(it)+B(it+2)
//    still in flight (vmcnt ~30), never drains to 0 mid-loop.
// Block 256 thr = 4 waves, tile 112(m) x 64(n), wave w -> cols w*16..+15.
// ---------------------------------------------------------------------------
template<int NITER>
__global__ __launch_bounds__(256, 3)
void mm_kernel(const _Float16* __restrict__ A, const float* __restrict__ B,
               float* __restrict__ Cacc, int lda) {
    __shared__ __align__(16) _Float16 Bs[2][64 * 64];   // [buf][c*64 + swz k]

    const int t   = threadIdx.x;
    const int j0  = blockIdx.x * 64;
    const int k0  = blockIdx.y * (NITER * 64);
    const int w   = t >> 6;
    const int L   = t & 63;
    const int l15 = L & 15;
    const int q   = L >> 4;
    const int sc  = t & 63;        // staging column 0..63
    const int kg  = t >> 6;        // staging k-group (== wave id)
    const int swz = sc & 7;

    fx4 acc[7];
#pragma unroll
    for (int mt = 0; mt < 7; ++mt) acc[mt] = (fx4){0.f, 0.f, 0.f, 0.f};

    const float*    Bp  = B + (size_t)k0 * C + j0 + sc;
    const _Float16* Ap  = A + (size_t)l15 * lda + k0;
    _Float16*       BsW = &Bs[0][0] + sc * 64;
    const _Float16* BsR = &Bs[0][0] + (w * 16 + l15) * 64;

    float bva[16], bvb[16];

#define LOADB(dst, ch)                                                         \
    { _Pragma("unroll")                                                        \
      for (int p = 0; p < 16; ++p)                                             \
          dst[p] = Bp[(size_t)((ch) * 64 + kg * 16 + p) * C]; }

#define COMMITB(src, buf)                                                      \
    { _Pragma("unroll")                                                        \
      for (int p2 = 0; p2 < 2; ++p2) {                                         \
          f16x8 hv;                                                            \
          _Pragma("unroll")                                                    \
          for (int e = 0; e < 8; ++e) hv[e] = (_Float16)src[p2 * 8 + e];       \
          *(f16x8*)(BsW + (buf) * 4096 + (((kg * 2 + p2) ^ swz) << 3)) = hv;   \
      } }

    // prologue: chunk0 -> Bs[0]; chunk1 staged in bva
    LOADB(bva, 0);
    COMMITB(bva, 0);
    LOADB(bva, 1);
    __syncthreads();

#pragma unroll
    for (int it = 0; it < NITER; ++it) {
        // A-fragments for this iter (issued FIRST so their waits leave B in flight)
        f16x8 af[2][7];
#pragma unroll
        for (int s = 0; s < 2; ++s)
#pragma unroll
            for (int mt = 0; mt < 7; ++mt)
                af[s][mt] = *(const f16x8*)(Ap + (size_t)mt * 16 * lda
                                            + it * 64 + s * 32 + q * 8);
        __builtin_amdgcn_sched_barrier(0);
        // issue B loads for chunk it+2 (newest; stays outstanding through MFMA)
        if (it + 2 < NITER) {
            if (it & 1) { LOADB(bva, it + 2); } else { LOADB(bvb, it + 2); }
        }
        __builtin_amdgcn_sched_barrier(0);
        // MFMA on current buffer
#pragma unroll
        for (int s = 0; s < 2; ++s) {
            f16x8 bf = *(const f16x8*)(BsR + (it & 1) * 4096
                            + ((((s << 2) + q) ^ (l15 & 7)) << 3));
#pragma unroll
            for (int mt = 0; mt < 7; ++mt)
                acc[mt] = __builtin_amdgcn_mfma_f32_16x16x32_f16(
                    af[s][mt], bf, acc[mt], 0, 0, 0);
        }
        // commit chunk it+1 (staged a FULL iter ago -> counted vmcnt, ~hidden)
        if (it + 1 < NITER) {
            if (it & 1) { COMMITB(bvb, (it + 1) & 1); }
            else        { COMMITB(bva, (it + 1) & 1); }
        }
        __syncthreads();
        // hazard: COMMIT writes buf[(it+1)&1], last read in iter it-1,
        // separated by the barrier at end of iter it-1 -> 1 barrier/iter safe.
    }

    // epilogue: fp32 atomic accumulate (C/D: col=lane&15, row=q*4+reg)
    const int col = j0 + w * 16 + l15;
#pragma unroll
    for (int mt = 0; mt < 7; ++mt)
#pragma unroll
        for (int r = 0; r < 4; ++r) {
            int row = mt * 16 + q * 4 + r;
            if (row < NN)
                atomicAdd(&Cacc[(size_t)row * C + col], acc[mt][r]);
        }
#undef LOADB
#undef COMMITB
}

// ---------------------------------------------------------------------------
// agg: per 16-col tile, builds A3 = fp16([h+b2, aggr]) [112][8192], u32 stores
// (masks/degrees precomputed by maskprep)
// ---------------------------------------------------------------------------
__global__ __launch_bounds__(256)
void agg_kernel(const float* __restrict__ h_raw, const ull* __restrict__ gmlo,
                const ull* __restrict__ gmhi, const float* __restrict__ gdegs,
                const float* __restrict__ b2, _Float16* __restrict__ A3) {
    __shared__ float hb[NN * 16];
    const int t  = threadIdx.x;
    const int c0 = blockIdx.x * 16;

    // load h tile (+bias) as pairs, emit A3 first half
    for (int idx = t; idx < NN * 8; idx += 256) {
        int n = idx >> 3, cp = (idx & 7) << 1;
        float2 v = *(const float2*)(h_raw + (size_t)n * C + c0 + cp);
        float v0 = v.x + b2[c0 + cp];
        float v1 = v.y + b2[c0 + cp + 1];
        hb[n * 16 + cp]     = v0;
        hb[n * 16 + cp + 1] = v1;
        union { _Float16 h[2]; unsigned u; } pk;
        pk.h[0] = (_Float16)v0;
        pk.h[1] = (_Float16)v1;
        *(unsigned*)(A3 + (size_t)n * (2 * C) + c0 + cp) = pk.u;
    }
    // zero pad rows 110,111 (both halves of this c-tile)
    if (t < 32) {
        int n  = NN + (t >> 4);
        int hs = (t >> 3) & 1;
        int cp = (t & 7) << 1;
        *(unsigned*)(A3 + (size_t)n * (2 * C) + hs * C + c0 + cp) = 0u;
    }
    __syncthreads();
    // aggr -> A3 second half (2 cols per thread-slot)
    for (int idx = t; idx < NN * 8; idx += 256) {
        int j = idx >> 3, cp = (idx & 7) << 1;
        ull lo = gmlo[j], hi = gmhi[j];
        float dg = gdegs[j];
        float a0 = 0.f, a1 = 0.f;
        for (int i = 0; i < 64; ++i)
            if ((lo >> i) & 1) { a0 += hb[i * 16 + cp]; a1 += hb[i * 16 + cp + 1]; }
        for (int i = 64; i < NN; ++i)
            if ((hi >> (i - 64)) & 1) { a0 += hb[i * 16 + cp]; a1 += hb[i * 16 + cp + 1]; }
        union { _Float16 h[2]; unsigned u; } pk;
        pk.h[0] = (_Float16)(a0 / dg);
        pk.h[1] = (_Float16)(a1 / dg);
        *(unsigned*)(A3 + (size_t)j * (2 * C) + C + c0 + cp) = pk.u;
    }
}

// ---------------------------------------------------------------------------
// fin: out[j,c] = sum_k Wl[j,k] * relu(z_raw[k,c]+b1[c]) + bl[j]
// grid (64 c-tiles, 4 j-slabs); each block reuses its zs stage for 7 j-groups.
// ---------------------------------------------------------------------------
__global__ __launch_bounds__(256)
void fin_kernel(const float* __restrict__ z_raw, const float* __restrict__ b1,
                const float* __restrict__ Wl, const float* __restrict__ bl,
                float* __restrict__ out) {
    __shared__ float zs[NN * 64];
    const int t  = threadIdx.x;
    const int c0 = blockIdx.x * 64;
    const int c  = t & 63;

    for (int idx = t; idx < NN * 64; idx += 256) {
        int k = idx >> 6, cc = idx & 63;
        float v = z_raw[(size_t)k * C + c0 + cc] + b1[c0 + cc];
        zs[idx] = fmaxf(v, 0.f);
    }
    __syncthreads();
    for (int jj = 0; jj < 7; ++jj) {
        int j = blockIdx.y * 28 + jj * 4 + (t >> 6);
        if (j < NN) {
            float a = bl[j];
#pragma unroll 2
            for (int k = 0; k < NN; ++k)
                a += Wl[j * NN + k] * zs[k * 64 + c];   // Wl wave-uniform -> scalar
            out[(size_t)j * C + c0 + c] = a;
        }
    }
}

// ---------------------------------------------------------------------------
extern "C" void kernel_launch(void* const* d_in, const int* in_sizes, int n_in,
                              void* d_out, int out_size, void* d_ws, size_t ws_size,
                              hipStream_t stream) {
    const float* x   = (const float*)d_in[0];
    const int*   adj = (const int*)d_in[1];
    const float* W2  = (const float*)d_in[2];
    const float* b2  = (const float*)d_in[3];
    const float* W1  = (const float*)d_in[4];
    const float* b1  = (const float*)d_in[5];
    const float* Wl  = (const float*)d_in[6];
    const float* bl  = (const float*)d_in[7];
    float* out = (float*)d_out;

    char* ws = (char*)d_ws;
    float*    h_raw = (float*)(ws);                    // 110*4096 f32
    float*    z_raw = (float*)(ws + 1802240);          // 110*4096 f32
    _Float16* A1    = (_Float16*)(ws + 3604480);       // 112*4096 f16
    _Float16* A3    = (_Float16*)(ws + 4521984);       // 112*8192 f16
    ull*      mlo   = (ull*)(ws + 6356992);            // 110 u64
    ull*      mhi   = (ull*)(ws + 6357872);            // 110 u64
    float*    degs  = (float*)(ws + 6358752);          // 110 f32

    hipMemsetAsync(d_ws, 0, 3604480, stream);                        // zero h_raw,z_raw
    prep1_kernel<<<(MPAD * C / 2) / 256, 256, 0, stream>>>(x, A1);
    maskprep_kernel<<<1, 128, 0, stream>>>(adj, mlo, mhi, degs);
    mm_kernel<4><<<dim3(64, 16), 256, 0, stream>>>(A1, W2, h_raw, C);
    agg_kernel<<<C / 16, 256, 0, stream>>>(h_raw, mlo, mhi, degs, b2, A3);
    mm_kernel<8><<<dim3(64, 16), 256, 0, stream>>>(A3, W1, z_raw, 2 * C);
    fin_kernel<<<dim3(C / 64, 4), 256, 0, stream>>>(z_raw, b1, Wl, bl, out);
}